// Round 1
// baseline (112.647 us; speedup 1.0000x reference)
//
#include <hip/hip_runtime.h>
#include <hip/hip_bf16.h>

// B=4, N=256, H=128, E=32
// M = B*N*N = 262144 rows. out[m][128] f32.

typedef __attribute__((ext_vector_type(8))) short bf16x8;
typedef __attribute__((ext_vector_type(4))) short bf16x4;
typedef __attribute__((ext_vector_type(4))) float f32x4;

__device__ __forceinline__ unsigned short f2bf(float f) {
  union { float f; unsigned u; } v; v.f = f;
  unsigned r = v.u + 0x7FFFu + ((v.u >> 16) & 1u);  // RNE
  return (unsigned short)(r >> 16);
}

// ---------------- prep: S = node@W1s + b1 ; DT[b][k][j] = (node@W1d)^T ; bf16 transposed weights ----
__global__ void prep_kernel(const float* __restrict__ node, const float* __restrict__ W1,
                            const float* __restrict__ b1, const float* __restrict__ W2,
                            float* __restrict__ S, float* __restrict__ DT,
                            unsigned short* __restrict__ W1hT, unsigned short* __restrict__ W1eT,
                            unsigned short* __restrict__ W2T) {
  const int t = threadIdx.x;
  if (blockIdx.x < 64) {
    __shared__ float nrow[16 * 128];
    const int bi0 = blockIdx.x * 16;
    const float4* src = reinterpret_cast<const float4*>(node + bi0 * 128);
    float4* dst = reinterpret_cast<float4*>(nrow);
    dst[t] = src[t];
    dst[t + 256] = src[t + 256];
    __syncthreads();
    const int kc = t & 127, half = t >> 7;
    float s[8], d[8];
#pragma unroll
    for (int r = 0; r < 8; ++r) { s[r] = 0.f; d[r] = 0.f; }
    for (int h = 0; h < 128; ++h) {
      float ws = W1[h * 128 + kc];
      float wd = W1[(128 + h) * 128 + kc];
#pragma unroll
      for (int r = 0; r < 8; ++r) {
        float nv = nrow[(half * 8 + r) * 128 + h];
        s[r] = fmaf(nv, ws, s[r]);
        d[r] = fmaf(nv, wd, d[r]);
      }
    }
    const float bv = b1[kc];
    const int b = bi0 >> 8, i0 = bi0 & 255;
#pragma unroll
    for (int r = 0; r < 8; ++r) {
      int row = half * 8 + r;
      S[(bi0 + row) * 128 + kc] = s[r] + bv;
      DT[(b * 128 + kc) * 256 + i0 + row] = d[r];
    }
  } else {
    int gid = (blockIdx.x - 64) * 256 + t;
    for (int idx = gid; idx < 16384; idx += 2048)
      W1hT[idx] = f2bf(W1[(256 + (idx & 127)) * 128 + (idx >> 7)]);
    for (int idx = gid; idx < 4096; idx += 2048)
      W1eT[idx] = f2bf(W1[(384 + (idx & 31)) * 128 + (idx >> 5)]);
    for (int idx = gid; idx < 16384; idx += 2048)
      W2T[idx] = f2bf(W2[(idx & 127) * 128 + (idx >> 7)]);
  }
}

// ---------------- fused main kernel ----------------
#define LDD 136  // dart/h LDS row stride in ushorts (128 + 8 pad -> 272B, 17*16B)
#define LDE 40   // edge LDS row stride (32 + 8 pad -> 80B, 5*16B)

__launch_bounds__(256, 2)
__global__ void fused_kernel(const float* __restrict__ dart, const float* __restrict__ edge,
                             const float* __restrict__ S, const float* __restrict__ DT,
                             const unsigned short* __restrict__ W1hT,
                             const unsigned short* __restrict__ W1eT,
                             const unsigned short* __restrict__ W2T,
                             const float* __restrict__ b2, float* __restrict__ out) {
  __shared__ unsigned short sDart[64 * LDD];
  __shared__ unsigned short sEdge[64 * LDE];
  __shared__ unsigned short sH[64 * LDD];

  const int tid = threadIdx.x;
  const int lane = tid & 63;
  const int w = tid >> 6;      // wave 0..3
  const int g = lane >> 4;     // 16-lane group 0..3
  const int lj = lane & 15;

  // --- preload weight fragments into registers (constant for whole kernel) ---
  bf16x8 wh[2][4], w2f[4][2], we[2];
#pragma unroll
  for (int kt = 0; kt < 2; ++kt)
#pragma unroll
    for (int hs = 0; hs < 4; ++hs)
      wh[kt][hs] = *reinterpret_cast<const bf16x8*>(&W1hT[(w * 32 + kt * 16 + lj) * 128 + hs * 32 + g * 8]);
#pragma unroll
  for (int kt = 0; kt < 2; ++kt)
    we[kt] = *reinterpret_cast<const bf16x8*>(&W1eT[(w * 32 + kt * 16 + lj) * 32 + g * 8]);
#pragma unroll
  for (int ks = 0; ks < 4; ++ks)
#pragma unroll
    for (int nt = 0; nt < 2; ++nt)
      w2f[ks][nt] = *reinterpret_cast<const bf16x8*>(&W2T[(w * 32 + nt * 16 + lj) * 128 + ks * 32 + g * 8]);
  float b2v[2];
  b2v[0] = b2[w * 32 + lj];
  b2v[1] = b2[w * 32 + 16 + lj];

  for (int tile = blockIdx.x; tile < 4096; tile += gridDim.x) {
    const int m0 = tile * 64;
    const int bi = m0 >> 8;        // b*256 + i
    const int b = bi >> 8;
    const int j0 = m0 & 255;

    // --- stage dart & edge tile -> LDS (f32 -> bf16) ---
    {
      const int row = tid >> 2, c0 = (tid & 3) * 32;
      const float4* src = reinterpret_cast<const float4*>(dart + (size_t)(m0 + row) * 128 + c0);
#pragma unroll
      for (int p = 0; p < 4; ++p) {
        float4 a = src[2 * p], c = src[2 * p + 1];
        bf16x8 pk;
        pk[0] = (short)f2bf(a.x); pk[1] = (short)f2bf(a.y);
        pk[2] = (short)f2bf(a.z); pk[3] = (short)f2bf(a.w);
        pk[4] = (short)f2bf(c.x); pk[5] = (short)f2bf(c.y);
        pk[6] = (short)f2bf(c.z); pk[7] = (short)f2bf(c.w);
        *reinterpret_cast<bf16x8*>(&sDart[row * LDD + c0 + p * 8]) = pk;
      }
      const int e0 = (tid & 3) * 8;
      const float4* esrc = reinterpret_cast<const float4*>(edge + (size_t)(m0 + row) * 32 + e0);
      float4 a = esrc[0], c = esrc[1];
      bf16x8 pk;
      pk[0] = (short)f2bf(a.x); pk[1] = (short)f2bf(a.y);
      pk[2] = (short)f2bf(a.z); pk[3] = (short)f2bf(a.w);
      pk[4] = (short)f2bf(c.x); pk[5] = (short)f2bf(c.y);
      pk[6] = (short)f2bf(c.z); pk[7] = (short)f2bf(c.w);
      *reinterpret_cast<bf16x8*>(&sEdge[row * LDE + e0]) = pk;
    }
    __syncthreads();

    // --- GEMM1 (swapped): pre^T[kc][j], wave owns kc-slice [w*32, w*32+32) ---
    f32x4 acc1[2][4];
#pragma unroll
    for (int kt = 0; kt < 2; ++kt)
#pragma unroll
      for (int jt = 0; jt < 4; ++jt) acc1[kt][jt] = (f32x4){0.f, 0.f, 0.f, 0.f};

#pragma unroll
    for (int hs = 0; hs < 4; ++hs) {
#pragma unroll
      for (int jt = 0; jt < 4; ++jt) {
        bf16x8 bd = *reinterpret_cast<const bf16x8*>(&sDart[(jt * 16 + lj) * LDD + hs * 32 + g * 8]);
        acc1[0][jt] = __builtin_amdgcn_mfma_f32_16x16x32_bf16(wh[0][hs], bd, acc1[0][jt], 0, 0, 0);
        acc1[1][jt] = __builtin_amdgcn_mfma_f32_16x16x32_bf16(wh[1][hs], bd, acc1[1][jt], 0, 0, 0);
      }
    }
#pragma unroll
    for (int jt = 0; jt < 4; ++jt) {
      bf16x8 be = *reinterpret_cast<const bf16x8*>(&sEdge[(jt * 16 + lj) * LDE + g * 8]);
      acc1[0][jt] = __builtin_amdgcn_mfma_f32_16x16x32_bf16(we[0], be, acc1[0][jt], 0, 0, 0);
      acc1[1][jt] = __builtin_amdgcn_mfma_f32_16x16x32_bf16(we[1], be, acc1[1][jt], 0, 0, 0);
    }

    // --- add S (per i) + D (per j), relu, pack h -> LDS [j][kc] bf16 ---
    {
      const float* Sp = S + bi * 128 + w * 32;
      const float* DTp = DT + ((b * 128 + w * 32) * 256) + j0;
#pragma unroll
      for (int kt = 0; kt < 2; ++kt) {
        float sv[4];
#pragma unroll
        for (int r = 0; r < 4; ++r) sv[r] = Sp[kt * 16 + g * 4 + r];
#pragma unroll
        for (int jt = 0; jt < 4; ++jt) {
          bf16x4 hp;
#pragma unroll
          for (int r = 0; r < 4; ++r) {
            int kc = kt * 16 + g * 4 + r;
            float dv = DTp[kc * 256 + jt * 16 + lj];
            float x = acc1[kt][jt][r] + sv[r] + dv;
            x = x > 0.f ? x : 0.f;
            hp[r] = (short)f2bf(x);
          }
          *reinterpret_cast<bf16x4*>(&sH[(jt * 16 + lj) * LDD + w * 32 + kt * 16 + g * 4]) = hp;
        }
      }
    }
    __syncthreads();

    // --- GEMM2: out[j][n], wave owns n-slice [w*32, w*32+32) ---
    f32x4 acc2[4][2];
#pragma unroll
    for (int jt = 0; jt < 4; ++jt)
#pragma unroll
      for (int nt = 0; nt < 2; ++nt) acc2[jt][nt] = (f32x4){0.f, 0.f, 0.f, 0.f};

#pragma unroll
    for (int ks = 0; ks < 4; ++ks) {
#pragma unroll
      for (int jt = 0; jt < 4; ++jt) {
        bf16x8 ah = *reinterpret_cast<const bf16x8*>(&sH[(jt * 16 + lj) * LDD + ks * 32 + g * 8]);
        acc2[jt][0] = __builtin_amdgcn_mfma_f32_16x16x32_bf16(ah, w2f[ks][0], acc2[jt][0], 0, 0, 0);
        acc2[jt][1] = __builtin_amdgcn_mfma_f32_16x16x32_bf16(ah, w2f[ks][1], acc2[jt][1], 0, 0, 0);
      }
    }

    // --- store (f32) ---
    float* op = out + (size_t)m0 * 128 + w * 32;
#pragma unroll
    for (int jt = 0; jt < 4; ++jt)
#pragma unroll
      for (int nt = 0; nt < 2; ++nt)
#pragma unroll
        for (int r = 0; r < 4; ++r)
          op[(size_t)(jt * 16 + g * 4 + r) * 128 + nt * 16 + lj] = acc2[jt][nt][r] + b2v[nt];
    // no trailing barrier needed: next-iter staging touches sDart/sEdge only after
    // this iter's bar2 (all waves done with GEMM1 reads); sH writes come after next bar1.
  }
}

extern "C" void kernel_launch(void* const* d_in, const int* in_sizes, int n_in,
                              void* d_out, int out_size, void* d_ws, size_t ws_size,
                              hipStream_t stream) {
  const float* node = (const float*)d_in[0];
  const float* dart = (const float*)d_in[1];
  const float* edge = (const float*)d_in[2];
  const float* W1   = (const float*)d_in[3];
  const float* b1   = (const float*)d_in[4];
  const float* W2   = (const float*)d_in[5];
  const float* b2   = (const float*)d_in[6];
  float* out = (float*)d_out;

  // workspace layout
  float* S  = (float*)d_ws;                       // 131072 f32
  float* DT = S + 131072;                         // 131072 f32
  unsigned short* W1hT = (unsigned short*)(DT + 131072);  // 16384 bf16
  unsigned short* W1eT = W1hT + 16384;            // 4096 bf16
  unsigned short* W2T  = W1eT + 4096;             // 16384 bf16

  hipLaunchKernelGGL(prep_kernel, dim3(72), dim3(256), 0, stream,
                     node, W1, b1, W2, S, DT, W1hT, W1eT, W2T);
  hipLaunchKernelGGL(fused_kernel, dim3(4096), dim3(256), 0, stream,
                     dart, edge, S, DT, W1hT, W1eT, W2T, b2, out);
}

// Round 2
// 93.808 us; speedup vs baseline: 1.2008x; 1.2008x over previous
//
#include <hip/hip_runtime.h>
#include <hip/hip_bf16.h>

// B=4, N=256, H=128, E=32. M = B*N*N = 262144 rows, out[m][128] f32.

typedef __attribute__((ext_vector_type(8))) short bf16x8;
typedef __attribute__((ext_vector_type(4))) short bf16x4;
typedef __attribute__((ext_vector_type(4))) float f32x4;

__device__ __forceinline__ unsigned short f2bf(float f) {
  union { float f; unsigned u; } v; v.f = f;
  unsigned r = v.u + 0x7FFFu + ((v.u >> 16) & 1u);  // RNE
  return (unsigned short)(r >> 16);
}

// ---------------- prep: S = node@W1s + b1 ; DT[b][k][j] = (node@W1d)^T ; bf16 transposed weights ----
__global__ void prep_kernel(const float* __restrict__ node, const float* __restrict__ W1,
                            const float* __restrict__ b1, const float* __restrict__ W2,
                            float* __restrict__ S, float* __restrict__ DT,
                            unsigned short* __restrict__ W1hT, unsigned short* __restrict__ W1eT,
                            unsigned short* __restrict__ W2T) {
  const int t = threadIdx.x;
  if (blockIdx.x < 256) {
    __shared__ float nrow[4 * 128];
    const int bi0 = blockIdx.x * 4;
    if (t < 128)
      reinterpret_cast<float4*>(nrow)[t] = reinterpret_cast<const float4*>(node + bi0 * 128)[t];
    __syncthreads();
    const int kc = t & 127, half = t >> 7;  // rows half*2, half*2+1
    float s0 = 0.f, s1 = 0.f, d0 = 0.f, d1 = 0.f;
    for (int h = 0; h < 128; ++h) {
      float ws = W1[h * 128 + kc];
      float wd = W1[(128 + h) * 128 + kc];
      float n0 = nrow[(half * 2) * 128 + h];
      float n1 = nrow[(half * 2 + 1) * 128 + h];
      s0 = fmaf(n0, ws, s0); s1 = fmaf(n1, ws, s1);
      d0 = fmaf(n0, wd, d0); d1 = fmaf(n1, wd, d1);
    }
    const float bv = b1[kc];
    const int b = bi0 >> 8, i0 = bi0 & 255;
    S[(bi0 + half * 2) * 128 + kc] = s0 + bv;
    S[(bi0 + half * 2 + 1) * 128 + kc] = s1 + bv;
    DT[(b * 128 + kc) * 256 + i0 + half * 2] = d0;
    DT[(b * 128 + kc) * 256 + i0 + half * 2 + 1] = d1;
  } else {
    int gid = (blockIdx.x - 256) * 256 + t;
    for (int idx = gid; idx < 16384; idx += 2048)
      W1hT[idx] = f2bf(W1[(256 + (idx & 127)) * 128 + (idx >> 7)]);
    for (int idx = gid; idx < 4096; idx += 2048)
      W1eT[idx] = f2bf(W1[(384 + (idx & 31)) * 128 + (idx >> 5)]);
    for (int idx = gid; idx < 16384; idx += 2048)
      W2T[idx] = f2bf(W2[(idx & 127) * 128 + (idx >> 7)]);
  }
}

// ---------------- fused main kernel ----------------
#define LDD 136  // dart/h LDS row stride in ushorts (272B)
#define LDE 40   // edge LDS row stride (80B)

__launch_bounds__(256, 2)
__global__ void fused_kernel(const float* __restrict__ dart, const float* __restrict__ edge,
                             const float* __restrict__ S, const float* __restrict__ DT,
                             const unsigned short* __restrict__ W1hT,
                             const unsigned short* __restrict__ W1eT,
                             const unsigned short* __restrict__ W2T,
                             const float* __restrict__ b2, float* __restrict__ out) {
  __shared__ unsigned short sDart[64 * LDD];
  __shared__ unsigned short sEdge[64 * LDE];
  __shared__ unsigned short sH[64 * LDD];

  const int tid = threadIdx.x;
  const int lane = tid & 63;
  const int w = tid >> 6;      // wave 0..3
  const int g = lane >> 4;     // 16-lane group 0..3
  const int lj = lane & 15;

  const int bi = blockIdx.x;   // 0..1023 = b*256 + i
  const int b = bi >> 8;
  const size_t m_base = (size_t)bi * 256;

  // --- per-block constants in registers ---
  bf16x8 wh[2][4], w2f[4][2], we[2];
#pragma unroll
  for (int kt = 0; kt < 2; ++kt)
#pragma unroll
    for (int hs = 0; hs < 4; ++hs)
      wh[kt][hs] = *reinterpret_cast<const bf16x8*>(&W1hT[(w * 32 + kt * 16 + lj) * 128 + hs * 32 + g * 8]);
#pragma unroll
  for (int kt = 0; kt < 2; ++kt)
    we[kt] = *reinterpret_cast<const bf16x8*>(&W1eT[(w * 32 + kt * 16 + lj) * 32 + g * 8]);
#pragma unroll
  for (int ks = 0; ks < 4; ++ks)
#pragma unroll
    for (int nt = 0; nt < 2; ++nt)
      w2f[ks][nt] = *reinterpret_cast<const bf16x8*>(&W2T[(w * 32 + nt * 16 + lj) * 128 + ks * 32 + g * 8]);

  float sv[2][4], b2v[2][4];
#pragma unroll
  for (int kt = 0; kt < 2; ++kt)
#pragma unroll
    for (int r = 0; r < 4; ++r)
      sv[kt][r] = S[bi * 128 + w * 32 + kt * 16 + g * 4 + r];
#pragma unroll
  for (int nt = 0; nt < 2; ++nt)
#pragma unroll
    for (int r = 0; r < 4; ++r)
      b2v[nt][r] = b2[w * 32 + nt * 16 + g * 4 + r];

  const int srow = tid >> 2;          // staging row 0..63
  const int c0 = (tid & 3) * 32;      // dart col (floats)
  const int e0 = (tid & 3) * 8;       // edge col (floats)

  float4 rD[8], rE[2];

  // prologue: load + write tile 0
  {
    const float4* dsrc = reinterpret_cast<const float4*>(dart + (m_base + srow) * 128 + c0);
#pragma unroll
    for (int p = 0; p < 8; ++p) rD[p] = dsrc[p];
    const float4* esrc = reinterpret_cast<const float4*>(edge + (m_base + srow) * 32 + e0);
    rE[0] = esrc[0]; rE[1] = esrc[1];
  }
  {
#pragma unroll
    for (int p = 0; p < 4; ++p) {
      float4 a = rD[2 * p], c = rD[2 * p + 1];
      bf16x8 pk;
      pk[0] = (short)f2bf(a.x); pk[1] = (short)f2bf(a.y);
      pk[2] = (short)f2bf(a.z); pk[3] = (short)f2bf(a.w);
      pk[4] = (short)f2bf(c.x); pk[5] = (short)f2bf(c.y);
      pk[6] = (short)f2bf(c.z); pk[7] = (short)f2bf(c.w);
      *reinterpret_cast<bf16x8*>(&sDart[srow * LDD + c0 + p * 8]) = pk;
    }
    float4 a = rE[0], c = rE[1];
    bf16x8 pk;
    pk[0] = (short)f2bf(a.x); pk[1] = (short)f2bf(a.y);
    pk[2] = (short)f2bf(a.z); pk[3] = (short)f2bf(a.w);
    pk[4] = (short)f2bf(c.x); pk[5] = (short)f2bf(c.y);
    pk[6] = (short)f2bf(c.z); pk[7] = (short)f2bf(c.w);
    *reinterpret_cast<bf16x8*>(&sEdge[srow * LDE + e0]) = pk;
  }
  __syncthreads();

  for (int t = 0; t < 4; ++t) {
    const int j0 = t * 64;

    // --- hoist DT loads (used in pack; latency hides under GEMM1) ---
    float dv[2][4][4];
    {
      const float* DTp = DT + (size_t)(b * 128 + w * 32) * 256 + j0;
#pragma unroll
      for (int kt = 0; kt < 2; ++kt)
#pragma unroll
        for (int jt = 0; jt < 4; ++jt)
#pragma unroll
          for (int r = 0; r < 4; ++r)
            dv[kt][jt][r] = DTp[(kt * 16 + g * 4 + r) * 256 + jt * 16 + lj];
    }

    // --- issue next tile's global loads (consumed after GEMM2) ---
    if (t < 3) {
      const float4* dsrc = reinterpret_cast<const float4*>(dart + (m_base + j0 + 64 + srow) * 128 + c0);
#pragma unroll
      for (int p = 0; p < 8; ++p) rD[p] = dsrc[p];
      const float4* esrc = reinterpret_cast<const float4*>(edge + (m_base + j0 + 64 + srow) * 32 + e0);
      rE[0] = esrc[0]; rE[1] = esrc[1];
    }

    // --- GEMM1 (swapped): pre^T[kc][j], wave owns kc-slice [w*32, w*32+32) ---
    f32x4 acc1[2][4];
#pragma unroll
    for (int kt = 0; kt < 2; ++kt)
#pragma unroll
      for (int jt = 0; jt < 4; ++jt) acc1[kt][jt] = (f32x4){0.f, 0.f, 0.f, 0.f};

#pragma unroll
    for (int hs = 0; hs < 4; ++hs) {
#pragma unroll
      for (int jt = 0; jt < 4; ++jt) {
        bf16x8 bd = *reinterpret_cast<const bf16x8*>(&sDart[(jt * 16 + lj) * LDD + hs * 32 + g * 8]);
        acc1[0][jt] = __builtin_amdgcn_mfma_f32_16x16x32_bf16(wh[0][hs], bd, acc1[0][jt], 0, 0, 0);
        acc1[1][jt] = __builtin_amdgcn_mfma_f32_16x16x32_bf16(wh[1][hs], bd, acc1[1][jt], 0, 0, 0);
      }
    }
#pragma unroll
    for (int jt = 0; jt < 4; ++jt) {
      bf16x8 be = *reinterpret_cast<const bf16x8*>(&sEdge[(jt * 16 + lj) * LDE + e0 - (tid & 3) * 8 + g * 8]);
      acc1[0][jt] = __builtin_amdgcn_mfma_f32_16x16x32_bf16(we[0], be, acc1[0][jt], 0, 0, 0);
      acc1[1][jt] = __builtin_amdgcn_mfma_f32_16x16x32_bf16(we[1], be, acc1[1][jt], 0, 0, 0);
    }

    // --- add S (per i) + D (per j), relu, pack h -> sH [j][kc] bf16 ---
#pragma unroll
    for (int kt = 0; kt < 2; ++kt) {
#pragma unroll
      for (int jt = 0; jt < 4; ++jt) {
        bf16x4 hp;
#pragma unroll
        for (int r = 0; r < 4; ++r) {
          float x = acc1[kt][jt][r] + sv[kt][r] + dv[kt][jt][r];
          x = x > 0.f ? x : 0.f;
          hp[r] = (short)f2bf(x);
        }
        *reinterpret_cast<bf16x4*>(&sH[(jt * 16 + lj) * LDD + w * 32 + kt * 16 + g * 4]) = hp;
      }
    }
    __syncthreads();   // sH ready; all GEMM1 reads of sDart/sEdge done

    // --- GEMM2 (swapped): lane holds out[j][4 consecutive n] -> float4 stores ---
    f32x4 acc2[4][2];
#pragma unroll
    for (int jt = 0; jt < 4; ++jt)
#pragma unroll
      for (int nt = 0; nt < 2; ++nt) acc2[jt][nt] = (f32x4){0.f, 0.f, 0.f, 0.f};

#pragma unroll
    for (int ks = 0; ks < 4; ++ks) {
#pragma unroll
      for (int jt = 0; jt < 4; ++jt) {
        bf16x8 ah = *reinterpret_cast<const bf16x8*>(&sH[(jt * 16 + lj) * LDD + ks * 32 + g * 8]);
        acc2[jt][0] = __builtin_amdgcn_mfma_f32_16x16x32_bf16(w2f[ks][0], ah, acc2[jt][0], 0, 0, 0);
        acc2[jt][1] = __builtin_amdgcn_mfma_f32_16x16x32_bf16(w2f[ks][1], ah, acc2[jt][1], 0, 0, 0);
      }
    }

    // --- stage next tile into sDart/sEdge (safe: reads done at mid-barrier) ---
    if (t < 3) {
#pragma unroll
      for (int p = 0; p < 4; ++p) {
        float4 a = rD[2 * p], c = rD[2 * p + 1];
        bf16x8 pk;
        pk[0] = (short)f2bf(a.x); pk[1] = (short)f2bf(a.y);
        pk[2] = (short)f2bf(a.z); pk[3] = (short)f2bf(a.w);
        pk[4] = (short)f2bf(c.x); pk[5] = (short)f2bf(c.y);
        pk[6] = (short)f2bf(c.z); pk[7] = (short)f2bf(c.w);
        *reinterpret_cast<bf16x8*>(&sDart[srow * LDD + c0 + p * 8]) = pk;
      }
      float4 a = rE[0], c = rE[1];
      bf16x8 pk;
      pk[0] = (short)f2bf(a.x); pk[1] = (short)f2bf(a.y);
      pk[2] = (short)f2bf(a.z); pk[3] = (short)f2bf(a.w);
      pk[4] = (short)f2bf(c.x); pk[5] = (short)f2bf(c.y);
      pk[6] = (short)f2bf(c.z); pk[7] = (short)f2bf(c.w);
      *reinterpret_cast<bf16x8*>(&sEdge[srow * LDE + e0]) = pk;
    }

    // --- store (dwordx4) ---
    {
      float* op = out + (m_base + j0) * 128;
#pragma unroll
      for (int jt = 0; jt < 4; ++jt)
#pragma unroll
        for (int nt = 0; nt < 2; ++nt) {
          float4 v;
          v.x = acc2[jt][nt][0] + b2v[nt][0];
          v.y = acc2[jt][nt][1] + b2v[nt][1];
          v.z = acc2[jt][nt][2] + b2v[nt][2];
          v.w = acc2[jt][nt][3] + b2v[nt][3];
          *reinterpret_cast<float4*>(&op[(size_t)(jt * 16 + lj) * 128 + w * 32 + nt * 16 + g * 4]) = v;
        }
    }
    __syncthreads();   // sDart[t+1] staged; sH reads done
  }
}

extern "C" void kernel_launch(void* const* d_in, const int* in_sizes, int n_in,
                              void* d_out, int out_size, void* d_ws, size_t ws_size,
                              hipStream_t stream) {
  const float* node = (const float*)d_in[0];
  const float* dart = (const float*)d_in[1];
  const float* edge = (const float*)d_in[2];
  const float* W1   = (const float*)d_in[3];
  const float* b1   = (const float*)d_in[4];
  const float* W2   = (const float*)d_in[5];
  const float* b2   = (const float*)d_in[6];
  float* out = (float*)d_out;

  float* S  = (float*)d_ws;                       // 131072 f32
  float* DT = S + 131072;                         // 131072 f32
  unsigned short* W1hT = (unsigned short*)(DT + 131072);  // 16384 bf16
  unsigned short* W1eT = W1hT + 16384;            // 4096 bf16
  unsigned short* W2T  = W1eT + 4096;             // 16384 bf16

  hipLaunchKernelGGL(prep_kernel, dim3(264), dim3(256), 0, stream,
                     node, W1, b1, W2, S, DT, W1hT, W1eT, W2T);
  hipLaunchKernelGGL(fused_kernel, dim3(1024), dim3(256), 0, stream,
                     dart, edge, S, DT, W1hT, W1eT, W2T, b2, out);
}